// Round 2
// baseline (115.576 us; speedup 1.0000x reference)
//
#include <hip/hip_runtime.h>

// BoxDetectionLoss on MI355X.
// Decomposition:
//   Kernel A: sum of sigmoid(conf)^2 over all 6.29M anchors, reading ONLY the
//             3 conf channels per batch (25.2 MB of the 75.5 MB input).
//             Grid-stride float4 loads, per-block float partial -> d_ws.
//   Kernel B: 1 block. (1) 384-item match correction at candidate pixels
//             (pixels listed in target_boxes; dedup by (r,c); first-match
//             semantics; rintf == jnp.round half-to-even), (2) double-precision
//             reduce of the 1024 partials + correction, write sum/denom.

#define NB 1024
#define NT 256
// planes: (b in 0..7) x (a in 0..2) conf channels; each plane 512*512 floats
// = 65536 float4.  Total float4 = 24 * 65536 = 1572864 = NB*NT*6.

__device__ __forceinline__ float sigmoidf_(float x) {
    // 1/(1+exp(-x)), exp via hardware v_exp_f32 (<=1 ulp)
    float e = __builtin_amdgcn_exp2f(-1.4426950408889634f * x);
    return 1.0f / (1.0f + e);
}

__global__ __launch_bounds__(NT) void conf_sum_kernel(const float* __restrict__ pol,
                                                      float* __restrict__ partials) {
    const int tid = threadIdx.x;
    const int gid = blockIdx.x * NT + tid;
    const float4* p4 = (const float4*)pol;
    float acc = 0.f;
#pragma unroll
    for (int it = 0; it < 6; ++it) {
        int i = gid + it * (NB * NT);
        int plane = i >> 16;          // 0..23 (b*3+a); 65536 float4 per plane
        int off = i & 65535;          // consecutive lanes -> consecutive float4
        int b = plane / 3;
        int a = plane - 3 * b;
        int chan = b * 9 + a * 3 + 2; // conf channel
        float4 v = p4[((size_t)chan << 16) + off];
        float s0 = sigmoidf_(v.x);
        float s1 = sigmoidf_(v.y);
        float s2 = sigmoidf_(v.z);
        float s3 = sigmoidf_(v.w);
        acc += s0 * s0 + s1 * s1 + s2 * s2 + s3 * s3;
    }
    // wave64 reduce
#pragma unroll
    for (int o = 32; o; o >>= 1) acc += __shfl_down(acc, o);
    __shared__ float sw[NT / 64];
    if ((tid & 63) == 0) sw[tid >> 6] = acc;
    __syncthreads();
    if (tid == 0) partials[blockIdx.x] = sw[0] + sw[1] + sw[2] + sw[3];
}

__global__ __launch_bounds__(NT) void finish_kernel(const float* __restrict__ pol,
                                                    const int* __restrict__ tb,
                                                    const float* __restrict__ tp,
                                                    const float* __restrict__ partials,
                                                    float* __restrict__ out) {
    const int tid = threadIdx.x;
    double acc = 0.0;

    // ---- match correction: item = (b*16 + t)*3 + a, 384 items ----
    for (int it = tid; it < 384; it += NT) {
        int a = it % 3;
        int bt = it / 3;
        int t = bt & 15;
        int b = bt >> 4;
        const int* tbb = tb + b * 64;   // 16 boxes * 4
        int r = tbb[t * 4 + 0];
        int c = tbb[t * 4 + 1];
        // dedup: this pixel already handled at an earlier t with same (r,c).
        // Valid because the fidx scan below covers ALL 16 boxes, so the
        // result depends only on (b, r, c, a), not on which t introduced it.
        bool dup = false;
        for (int t2 = 0; t2 < t; ++t2)
            if (tbb[t2 * 4 + 0] == r && tbb[t2 * 4 + 1] == c) { dup = true; break; }
        if (dup) continue;

        size_t base = ((size_t)(b * 9 + a * 3)) << 18;  // plane stride 2^18 floats
        size_t pix = ((size_t)r << 9) + (size_t)c;
        float x0 = pol[base + pix];                 // delta_r logit
        float x1 = pol[base + (1 << 18) + pix];     // delta_c logit
        float x2 = pol[base + (2 << 18) + pix];     // conf logit
        float dr = sigmoidf_(x0) * 9.0f;
        float dc = sigmoidf_(x1) * 16.0f;
        float conf = sigmoidf_(x2);
        float pr2 = fminf((float)r + dr, 511.0f);   // lower clip redundant (r>=0, dr>=0)
        float pc2 = fminf((float)c + dc, 511.0f);
        int pr2i = (int)rintf(pr2);                 // round half-to-even == jnp.round
        int pc2i = (int)rintf(pc2);

        int fidx = -1;
        for (int t2 = 0; t2 < 16; ++t2) {
            if (tbb[t2 * 4 + 0] == r && tbb[t2 * 4 + 1] == c &&
                tbb[t2 * 4 + 2] == pr2i && tbb[t2 * 4 + 3] == pc2i) { fidx = t2; break; }
        }
        if (fidx >= 0) {
            float tr2 = (float)tbb[fidx * 4 + 2];
            float tc2 = (float)tbb[fidx * 4 + 3];
            float tpv = tp[b * 16 + fidx];
            float coord = fabsf(pr2 - tr2) + fabsf(pc2 - tc2);
            float closs = (conf - tpv) * (conf - tpv);
            acc += (double)(coord + closs - conf * conf);
        }
    }

    // ---- fold in per-block partials ----
    for (int j = tid; j < NB; j += NT) acc += (double)partials[j];

    // block reduce (double)
#pragma unroll
    for (int o = 32; o; o >>= 1) acc += __shfl_down(acc, o);
    __shared__ double sd[NT / 64];
    if ((tid & 63) == 0) sd[tid >> 6] = acc;
    __syncthreads();
    if (tid == 0) {
        double total = sd[0] + sd[1] + sd[2] + sd[3];
        out[0] = (float)(total / 6291456.0);  // denom = 8*512*512*3
    }
}

extern "C" void kernel_launch(void* const* d_in, const int* in_sizes, int n_in,
                              void* d_out, int out_size, void* d_ws, size_t ws_size,
                              hipStream_t stream) {
    const float* pol = (const float*)d_in[0];   // (8,9,512,512) f32
    const int* tb = (const int*)d_in[1];        // (8,16,4) i32
    const float* tp = (const float*)d_in[2];    // (8,16) f32
    float* partials = (float*)d_ws;             // NB floats
    float* out = (float*)d_out;                 // 1 float

    conf_sum_kernel<<<NB, NT, 0, stream>>>(pol, partials);
    finish_kernel<<<1, NT, 0, stream>>>(pol, tb, tp, partials, out);
}